// Round 3
// baseline (1785.760 us; speedup 1.0000x reference)
//
#include <hip/hip_runtime.h>
#include <hip/hip_bf16.h>
#include <hip/hip_fp16.h>
#include <cmath>

// Problem constants
#define BATCH   8
#define D_MODEL 512
#define N2      32
#define LSEQ    4096
#define NLAYERS 4
#define CIN     3
#define NBDL    (16777216u)   // BATCH*D_MODEL*LSEQ
#define PN      (D_MODEL * N2)            // params per layer
#define WN      (2 * D_MODEL * D_MODEL)   // weights per layer

typedef __attribute__((ext_vector_type(8))) short short8;   // 8 bf16 (4 VGPRs)
typedef __attribute__((ext_vector_type(4))) float floatx4;  // MFMA accum

// ---------------------------------------------------------------------------
// Static device scratch. Every buffer fully overwritten before read, each call.
// ---------------------------------------------------------------------------
__device__ float   g_h[NBDL];                                  // 64 MB h (B,D,L) fp32
__device__ __align__(16) __hip_bfloat16 g_yb[NBDL];            // 32 MB gelu out (B,D,L) bf16
__device__ __align__(16) __hip_bfloat16 g_yt[NBDL];            // 32 MB y^T (B,L,D) bf16
__device__ __align__(16) __hip_bfloat16 g_wb[NLAYERS * WN];    // 8 MB W bf16, all layers
__device__ float4  g_p[NLAYERS * PN];                          // SSM params, all layers
__device__ float2  g_carry[BATCH * D_MODEL * N2];              // 1 MB mid-seq carries
__device__ float   g_hm[BATCH * D_MODEL];                      // mean over L
__device__ int     g_flag;                                     // 1=fp32, 0=bf16, 2=fp16

__device__ __forceinline__ float bfbits2f(unsigned short u) {
    union { unsigned int i; float f; } x; x.i = ((unsigned int)u) << 16; return x.f;
}
__device__ __forceinline__ float halfbits2f(unsigned short u) {
    __half h; *(unsigned short*)&h = u; return __half2float(h);
}
__device__ __forceinline__ float ldin(const void* p, size_t i, int m) {
    if (m == 1) return ((const float*)p)[i];
    unsigned short u = ((const unsigned short*)p)[i];
    if (m == 0) return bfbits2f(u);
    return halfbits2f(u);
}
__device__ __forceinline__ unsigned int pk2(float a, float b) {
    __hip_bfloat16 ha = __float2bfloat16(a), hb = __float2bfloat16(b);
    unsigned short ua, ub;
    __builtin_memcpy(&ua, &ha, 2); __builtin_memcpy(&ub, &hb, 2);
    return (unsigned int)ua | ((unsigned int)ub << 16);
}

// Branchless erf-based exact GELU (A&S 7.1.26, |err| < 1.5e-7 — far below the
// bf16 store quantization of 2^-9 relative).
__device__ __forceinline__ float fast_gelu(float x) {
    float z = x * 0.70710678118654752f;
    float a = fabsf(z);
    float t = __builtin_amdgcn_rcpf(fmaf(0.3275911f, a, 1.0f));
    float p = t * fmaf(t, fmaf(t, fmaf(t, fmaf(t, 1.061405429f, -1.453152027f),
                                       1.421413741f), -0.284496736f), 0.254829592f);
    float e = __expf(-a * a);
    float er = fmaf(-p, e, 1.0f);            // erf(|z|)
    er = copysignf(er, z);
    float hx = 0.5f * x;
    return fmaf(hx, er, hx);
}

// ---------------------------------------------------------------------------
// 0) dtype probe on A_imag (= pi*arange(32) broadcast; elt[1]=pi, elt[3]=3pi)
// ---------------------------------------------------------------------------
__global__ void detect_kernel(const unsigned short* a) {
    if (threadIdx.x == 0) {
        unsigned short h1 = a[1], h3 = a[3];
        int f;
        if (h1 == 0x0000 && h3 == 0x4049) f = 1;   // fp32 layout
        else if (h1 == 0x4049)            f = 0;   // native bf16
        else if (h1 == 0x4248)            f = 2;   // native fp16
        else                              f = 1;
        g_flag = f;
    }
}

__global__ __launch_bounds__(256) void sentinel_kernel(float* out, float v) {
    out[blockIdx.x * 256 + threadIdx.x] = v;
}

// ---------------------------------------------------------------------------
// 1) Input projection
// ---------------------------------------------------------------------------
__global__ __launch_bounds__(256) void proj_kernel(const void* x, const void* Wproj,
                                                   const void* bproj, const void* pos) {
    const int m = g_flag;
    unsigned idx = blockIdx.x * 256 + threadIdx.x;
    int l = idx & (LSEQ - 1);
    int o = (idx >> 12) & (D_MODEL - 1);
    int b = idx >> 21;
    float acc = ldin(bproj, o, m) + ldin(pos, (size_t)l * D_MODEL + o, m);
#pragma unroll
    for (int c = 0; c < CIN; c++)
        acc = fmaf(ldin(Wproj, o * CIN + c, m),
                   ldin(x, (size_t)(b * CIN + c) * LSEQ + l, m), acc);
    g_h[idx] = acc;
}

// ---------------------------------------------------------------------------
// 2) SSM param prep — ALL layers in one launch.
// ---------------------------------------------------------------------------
__global__ __launch_bounds__(256) void prep_kernel(const void* log_dt, const void* log_A_real,
                                                   const void* A_imag, const void* C_re,
                                                   const void* C_im) {
    const int m = g_flag;
    int idx = blockIdx.x * 256 + threadIdx.x;        // over NLAYERS*PN
    int layer = idx >> 14;                           // PN = 16384
    int i = idx & (PN - 1);
    int hh = i >> 5;
    size_t oH = (size_t)layer * D_MODEL;
    size_t oN = (size_t)layer * PN;
    float dt  = expf(ldin(log_dt, oH + hh, m));
    float a   = expf(ldin(log_A_real, oN + i, m));
    float bi  = ldin(A_imag, oN + i, m);
    float dre = -a * dt, dim = bi * dt;
    float er  = expf(dre);
    float wr  = er * cosf(dim);
    float wi  = er * sinf(dim);
    float Er  = wr - 1.0f, Ei = wi;
    float inv = 1.0f / (a * a + bi * bi);
    float Tr = (-Er * a + Ei * bi) * inv;
    float Ti = -(Er * bi + Ei * a) * inv;
    float cr = ldin(C_re, oN + i, m), ci = ldin(C_im, oN + i, m);
    float c2r = 2.0f * (cr * Tr - ci * Ti);
    float c2i = 2.0f * (cr * Ti + ci * Tr);
    g_p[idx] = make_float4(wr, wi, c2r, c2i);
}

// ---------------------------------------------------------------------------
// 2b) Pack Wout to bf16 — ALL layers in one launch.
// ---------------------------------------------------------------------------
__global__ __launch_bounds__(256) void pack_w_kernel(const void* Wout) {
    int idx = blockIdx.x * 256 + threadIdx.x;        // over NLAYERS*WN
    g_wb[idx] = __float2bfloat16(ldin(Wout, idx, g_flag));
}

// ---------------------------------------------------------------------------
// 2c) Prescan v3: one block per seq; 8 groups each scan a 256-step chunk from
//     zero state (4-step doubling), then lanes 0..31 combine the 8 chunk
//     partials with a Horner over w^256.
// ---------------------------------------------------------------------------
__global__ __launch_bounds__(256) void prescan_kernel(int layer) {
    __shared__ float2 Lp[8][32];
    int tid  = threadIdx.x;
    int lane = tid & 31;                             // state index n
    int grp  = tid >> 5;                             // chunk index 0..7
    int seq  = blockIdx.x;                           // flat (b*512 + h)
    int hh   = seq & (D_MODEL - 1);
    float4 pv = g_p[(size_t)layer * PN + hh * N2 + lane];
    const float wr = pv.x, wi = pv.y;
    const float w2r = wr * wr - wi * wi,     w2i = 2.0f * wr * wi;
    const float w3r = w2r * wr - w2i * wi,   w3i = w2r * wi + w2i * wr;
    const float w4r = w2r * w2r - w2i * w2i, w4i = 2.0f * w2r * w2i;
    const float* __restrict__ u = g_h + (size_t)seq * LSEQ + grp * 256;
    float sr = 0.f, si = 0.f;
#pragma unroll 4
    for (int l0 = 0; l0 < 256; l0 += 4) {
        float4 uq = *(const float4*)&u[l0];
        float Er = fmaf(w3r, uq.x, fmaf(w2r, uq.y, fmaf(wr, uq.z, uq.w)));
        float Ei = fmaf(w3i, uq.x, fmaf(w2i, uq.y, wi * uq.z));
        float t  = fmaf(w4r, sr, fmaf(-w4i, si, Er));
        si = fmaf(w4i, sr, fmaf(w4r, si, Ei));
        sr = t;
    }
    Lp[grp][lane] = make_float2(sr, si);
    __syncthreads();
    if (tid < 32) {
        // w^256 from w^4 via 6 complex squarings
        float ar = w4r, ai = w4i;
#pragma unroll
        for (int s = 0; s < 6; s++) {
            float nr = ar * ar - ai * ai;
            ai = 2.0f * ar * ai;
            ar = nr;
        }
        float2 p0 = Lp[0][lane];
        float accr = p0.x, acci = p0.y;
#pragma unroll
        for (int g = 1; g < 8; g++) {
            float2 pg = Lp[g][lane];
            float nr = fmaf(accr, ar, fmaf(-acci, ai, pg.x));
            acci     = fmaf(accr, ai, fmaf(acci, ar, pg.y));
            accr = nr;
        }
        g_carry[seq * 32 + lane] = make_float2(accr, acci);
    }
}

// ---------------------------------------------------------------------------
// 3) SSM scan + Dskip + exact GELU — LDS transpose-reduce, register-resident.
//    16-step tiles: V[8][32][18] = 18 KB -> 8 blocks/CU = 32 waves/CU (was 4
//    blocks / 16 waves with 32-step tiles). Same per-step instruction budget:
//    float2 LDS writes (stride 18 keeps 8B alignment; 2-way bank alias = free),
//    1 b32 read/step (row offset 16*18 % 32 == 0 -> 2-way alias = free).
//    Cross-half reduce closes with one shfl_xor(16) within each 32-lane group.
// ---------------------------------------------------------------------------
__global__ __launch_bounds__(256, 8) void scan_kernel(const void* Dskip, int layer) {
    __shared__ float V[8][32][18];                   // 18 KB
    const int m = g_flag;
    int tid  = threadIdx.x;
    int lane = tid & 31;                             // state index n
    int grp  = tid >> 5;                             // 0..7
    int gid  = blockIdx.x * 8 + grp;                 // 0..8191 = seq*2 + half
    int seq  = gid >> 1;
    int half = gid & 1;
    int hh   = seq & (D_MODEL - 1);
    float4 pv = g_p[(size_t)layer * PN + hh * N2 + lane];
    const float wr = pv.x, wi = pv.y, c2r = pv.z, c2i = pv.w;
    const float dsk = ldin(Dskip, (size_t)layer * D_MODEL + hh, m);
    const float* __restrict__ u = g_h + (size_t)seq * LSEQ;
    __hip_bfloat16* __restrict__ y = g_yb + (size_t)seq * LSEQ;
    float (* __restrict__ Vg)[18] = V[grp];
    float sr = 0.f, si = 0.f;
    if (half) { float2 cv = g_carry[seq * 32 + lane]; sr = cv.x; si = cv.y; }
    const int t16 = lane & 15;                       // output step within tile
    const int hi  = lane >> 4;                       // which n-half this lane sums
    const int base = half << 11;
    for (int l0 = base; l0 < base + 2048; l0 += 16) {
#pragma unroll
        for (int q = 0; q < 4; q++) {
            float4 uq = *(const float4*)&u[l0 + q * 4];   // broadcast (same addr in group)
            float t;
            t  = fmaf(wr, sr, fmaf(-wi, si, uq.x));
            si = fmaf(wr, si, wi * sr); sr = t;
            float c0 = fmaf(c2r, sr, -c2i * si);
            t  = fmaf(wr, sr, fmaf(-wi, si, uq.y));
            si = fmaf(wr, si, wi * sr); sr = t;
            float c1 = fmaf(c2r, sr, -c2i * si);
            t  = fmaf(wr, sr, fmaf(-wi, si, uq.z));
            si = fmaf(wr, si, wi * sr); sr = t;
            float c2 = fmaf(c2r, sr, -c2i * si);
            t  = fmaf(wr, sr, fmaf(-wi, si, uq.w));
            si = fmaf(wr, si, wi * sr); sr = t;
            float c3 = fmaf(c2r, sr, -c2i * si);
            *(float2*)&Vg[lane][q * 4]     = make_float2(c0, c1);
            *(float2*)&Vg[lane][q * 4 + 2] = make_float2(c2, c3);
        }
        __builtin_amdgcn_wave_barrier();
        float acc = 0.f;
#pragma unroll
        for (int k = 0; k < 16; k++)
            acc += Vg[hi * 16 + k][t16];
        acc += __shfl_xor(acc, 16, 32);              // sum the two n-halves
        __builtin_amdgcn_wave_barrier();
        if (lane < 16) {
            float uv = u[l0 + t16];                  // L1-hit
            float yt = fmaf(dsk, uv, acc);
            y[l0 + t16] = __float2bfloat16(fast_gelu(yt));
        }
    }
}

// ---------------------------------------------------------------------------
// 3b) Transpose: g_yb[b][k][l] bf16 -> g_yt[b][l][k] bf16. 64x64 tiles.
// ---------------------------------------------------------------------------
__global__ __launch_bounds__(256) void transpose_y_kernel() {
    __shared__ float Ts[64][67];
    int tid = threadIdx.x;
    int b  = blockIdx.z;
    int l0 = blockIdx.x * 64;
    int k0 = blockIdx.y * 64;
    const unsigned short* __restrict__ src =
        (const unsigned short*)g_yb + (size_t)b * D_MODEL * LSEQ;
    int kr = tid >> 3;              // 0..31
    int cc = (tid & 7) * 8;         // 0..56 (l-offset, 8 elems)
#pragma unroll
    for (int sw = 0; sw < 2; sw++) {
        int k = kr + sw * 32;
        uint4 v = *(const uint4*)&src[(size_t)(k0 + k) * LSEQ + l0 + cc];
        Ts[k][cc + 0] = bfbits2f((unsigned short)(v.x & 0xFFFF));
        Ts[k][cc + 1] = bfbits2f((unsigned short)(v.x >> 16));
        Ts[k][cc + 2] = bfbits2f((unsigned short)(v.y & 0xFFFF));
        Ts[k][cc + 3] = bfbits2f((unsigned short)(v.y >> 16));
        Ts[k][cc + 4] = bfbits2f((unsigned short)(v.z & 0xFFFF));
        Ts[k][cc + 5] = bfbits2f((unsigned short)(v.z >> 16));
        Ts[k][cc + 6] = bfbits2f((unsigned short)(v.w & 0xFFFF));
        Ts[k][cc + 7] = bfbits2f((unsigned short)(v.w >> 16));
    }
    __syncthreads();
    int lw = tid >> 2;              // 0..63 output l-row
    int kq = (tid & 3) * 16;        // 0,16,32,48
    uint4 A, B;
    A.x = pk2(Ts[kq + 0][lw],  Ts[kq + 1][lw]);
    A.y = pk2(Ts[kq + 2][lw],  Ts[kq + 3][lw]);
    A.z = pk2(Ts[kq + 4][lw],  Ts[kq + 5][lw]);
    A.w = pk2(Ts[kq + 6][lw],  Ts[kq + 7][lw]);
    B.x = pk2(Ts[kq + 8][lw],  Ts[kq + 9][lw]);
    B.y = pk2(Ts[kq + 10][lw], Ts[kq + 11][lw]);
    B.z = pk2(Ts[kq + 12][lw], Ts[kq + 13][lw]);
    B.w = pk2(Ts[kq + 14][lw], Ts[kq + 15][lw]);
    __hip_bfloat16* __restrict__ dst = g_yt + (size_t)b * ((size_t)LSEQ * D_MODEL);
    size_t o = (size_t)(l0 + lw) * D_MODEL + k0 + kq;
    *(uint4*)&dst[o]     = A;
    *(uint4*)&dst[o + 8] = B;
}

// ---------------------------------------------------------------------------
// 4) MFMA GLU: O = Wbf * Yt^T (both halves), z=(a+ba)*sigmoid(b+bb), H += z.
//    XCD-aware swizzle: hardware XCD = bid % 8; the 8 consecutive blocks on
//    ONE XCD share the same 256 KB Yt tile.
// ---------------------------------------------------------------------------
__global__ __launch_bounds__(256) void glu_mfma_kernel(const void* bout, int layer) {
    __shared__ __hip_bfloat16 Wa[64][32];   // 4 KB  [o'][k']
    __shared__ __hip_bfloat16 Wb[64][32];   // 4 KB
    __shared__ __hip_bfloat16 Yt[256][32];  // 16 KB [l'][k']
    const int m = g_flag;
    int tid  = threadIdx.x;
    int wave = tid >> 6, lane = tid & 63;
    int q = lane >> 4, nm = lane & 15;
    int bid = blockIdx.x;                    // 0..1023
    int xcd = bid & 7;
    int qb  = bid >> 3;                      // 0..127
    int rt  = qb & 7;                        // 0..7   (64 o-rows)  fast within XCD
    int ct  = (xcd << 4) | (qb >> 3);        // 0..127 (256 l-cols) 16 per XCD
    int col0 = ct * 256;
    int row0 = rt * 64;
    int b  = col0 >> 12;                     // single batch per block
    int l0 = col0 & (LSEQ - 1);
    const __hip_bfloat16* __restrict__ Ybase = g_yt + (size_t)b * ((size_t)LSEQ * D_MODEL);
    const __hip_bfloat16* __restrict__ Wbase = g_wb + (size_t)layer * WN;

    floatx4 accA[4][4], accB[4][4];
    floatx4 zed = {0.f, 0.f, 0.f, 0.f};
#pragma unroll
    for (int i = 0; i < 4; i++)
#pragma unroll
        for (int j = 0; j < 4; j++) { accA[i][j] = zed; accB[i][j] = zed; }

    int sr = tid >> 2;              // 0..63
    int sk = (tid & 3) * 8;         // 0,8,16,24
    int wavecol = wave * 64;

    for (int k0 = 0; k0 < D_MODEL; k0 += 32) {
        *(uint4*)&Wa[sr][sk] = *(const uint4*)&Wbase[(size_t)(row0 + sr) * D_MODEL + k0 + sk];
        *(uint4*)&Wb[sr][sk] = *(const uint4*)&Wbase[(size_t)(row0 + sr + D_MODEL) * D_MODEL + k0 + sk];
#pragma unroll
        for (int it = 0; it < 4; it++) {
            int lr = it * 64 + sr;
            *(uint4*)&Yt[lr][sk] = *(const uint4*)&Ybase[(size_t)(l0 + lr) * D_MODEL + k0 + sk];
        }
        __syncthreads();
        short8 afa[4], afb[4];
#pragma unroll
        for (int mi = 0; mi < 4; mi++) {
            afa[mi] = *(short8*)&Wa[mi * 16 + nm][q * 8];
            afb[mi] = *(short8*)&Wb[mi * 16 + nm][q * 8];
        }
#pragma unroll
        for (int ni = 0; ni < 4; ni++) {
            short8 bf = *(short8*)&Yt[wavecol + ni * 16 + nm][q * 8];
#pragma unroll
            for (int mi = 0; mi < 4; mi++) {
                accA[mi][ni] = __builtin_amdgcn_mfma_f32_16x16x32_bf16(afa[mi], bf, accA[mi][ni], 0, 0, 0);
                accB[mi][ni] = __builtin_amdgcn_mfma_f32_16x16x32_bf16(afb[mi], bf, accB[mi][ni], 0, 0, 0);
            }
        }
        __syncthreads();
    }

    size_t boff = (size_t)layer * 2 * D_MODEL;
    float* __restrict__ Hb = g_h + (size_t)b * D_MODEL * LSEQ;
#pragma unroll
    for (int mi = 0; mi < 4; mi++) {
#pragma unroll
        for (int r = 0; r < 4; r++) {
            int o = row0 + mi * 16 + q * 4 + r;
            float ba  = ldin(bout, boff + o, m);
            float bb2 = ldin(bout, boff + o + D_MODEL, m);
#pragma unroll
            for (int ni = 0; ni < 4; ni++) {
                int l = l0 + wavecol + ni * 16 + nm;
                float aa = accA[mi][ni][r] + ba;
                float bv = accB[mi][ni][r] + bb2;
                float z  = aa * __builtin_amdgcn_rcpf(1.0f + __expf(-bv));
                Hb[(size_t)o * LSEQ + l] += z;
            }
        }
    }
}

// ---------------------------------------------------------------------------
// 5) LayerNorm over D, in place on g_h — 32-l tiles, 1024 blocks (16 w/CU).
// ---------------------------------------------------------------------------
__global__ __launch_bounds__(256) void ln_kernel(const void* g, const void* bt, int layer) {
    __shared__ float s_sum[8][32];
    __shared__ float s_sq[8][32];
    __shared__ float s_mu[32], s_rs[32];
    const int m = g_flag;
    int tid = threadIdx.x;
    int l  = tid & 31;
    int dg = tid >> 5;                   // 0..7 -> d range [dg*64, dg*64+64)
    int bl = blockIdx.x;                 // 0..1023 = b*128 + ltile
    int b  = bl >> 7;
    int l0 = (bl & 127) * 32;
    float* __restrict__ hp = g_h + (size_t)b * D_MODEL * LSEQ + l0 + l;
    size_t goff = (size_t)layer * D_MODEL;
    float sum = 0.f, sq = 0.f;
#pragma unroll 4
    for (int d = dg * 64; d < dg * 64 + 64; d++) {
        float v = hp[(size_t)d * LSEQ];
        sum += v; sq += v * v;
    }
    s_sum[dg][l] = sum; s_sq[dg][l] = sq;
    __syncthreads();
    if (tid < 32) {
        float s = 0.f, qq = 0.f;
#pragma unroll
        for (int gq = 0; gq < 8; gq++) { s += s_sum[gq][tid]; qq += s_sq[gq][tid]; }
        float mu = s * (1.0f / D_MODEL);
        float var = qq * (1.0f / D_MODEL) - mu * mu;
        s_mu[tid] = mu;
        s_rs[tid] = rsqrtf(var + 1e-5f);
    }
    __syncthreads();
    float mu = s_mu[l], rs = s_rs[l];
#pragma unroll 4
    for (int d = dg * 64; d < dg * 64 + 64; d++) {
        float v = hp[(size_t)d * LSEQ];
        hp[(size_t)d * LSEQ] = (v - mu) * rs * ldin(g, goff + d, m) + ldin(bt, goff + d, m);
    }
}

// ---------------------------------------------------------------------------
// 6) Mean over L: one block per (b,d)
// ---------------------------------------------------------------------------
__global__ __launch_bounds__(256) void mean_kernel() {
    int bd = blockIdx.x;
    int tid = threadIdx.x;
    const float* __restrict__ row = g_h + (size_t)bd * LSEQ;
    float s = 0.f;
    for (int l = tid; l < LSEQ; l += 256) s += row[l];
#pragma unroll
    for (int off = 32; off > 0; off >>= 1) s += __shfl_down(s, off, 64);
    __shared__ float red[4];
    if ((tid & 63) == 0) red[tid >> 6] = s;
    __syncthreads();
    if (tid == 0) g_hm[bd] = (red[0] + red[1] + red[2] + red[3]) * (1.0f / LSEQ);
}

// ---------------------------------------------------------------------------
// 7) Final stats head -> FP32 output (mu flat || log_sig flat)
// ---------------------------------------------------------------------------
__global__ __launch_bounds__(256) void stats_kernel(const void* Wst, const void* bst,
                                                    float* __restrict__ out) {
    const int m = g_flag;
    int idx = blockIdx.x * 256 + threadIdx.x;
    int b = idx >> 9, o = idx & (D_MODEL - 1);
    const float* __restrict__ hb = g_hm + b * D_MODEL;
    float acc = ldin(bst, o, m);
    for (int d = 0; d < D_MODEL; d++)
        acc = fmaf(hb[d], ldin(Wst, (size_t)o * D_MODEL + d, m), acc);
    int pos = (o < 256) ? (b * 256 + o) : (2048 + b * 256 + (o - 256));
    out[pos] = acc;
}

// ---------------------------------------------------------------------------
extern "C" void kernel_launch(void* const* d_in, const int* in_sizes, int n_in,
                              void* d_out, int out_size, void* d_ws, size_t ws_size,
                              hipStream_t stream) {
    static const int exp_sizes[16] = {98304, 1536, 512, 2097152, 2048, 65536, 65536,
                                      65536, 65536, 2048, 2097152, 4096, 2048, 2048,
                                      262144, 512};
    bool ok = (n_in == 16);
    if (ok) for (int i = 0; i < 16; i++) if (in_sizes[i] != exp_sizes[i]) { ok = false; break; }
    if (!ok) {
        sentinel_kernel<<<(out_size + 255) / 256, 256, 0, stream>>>((float*)d_out, 1000.0f);
        return;
    }
    if (out_size != 4096) {
        sentinel_kernel<<<(out_size + 255) / 256, 256, 0, stream>>>((float*)d_out, 300.0f);
        return;
    }

    const void* x          = d_in[0];
    const void* Wproj      = d_in[1];
    const void* bproj      = d_in[2];
    const void* pos        = d_in[3];
    const void* log_dt     = d_in[4];
    const void* log_A_real = d_in[5];
    const void* A_imag     = d_in[6];
    const void* C_re       = d_in[7];
    const void* C_im       = d_in[8];
    const void* Dskip      = d_in[9];
    const void* Wout       = d_in[10];
    const void* bout       = d_in[11];
    const void* ln_g       = d_in[12];
    const void* ln_b       = d_in[13];
    const void* Wstats     = d_in[14];
    const void* bstats     = d_in[15];

    detect_kernel<<<1, 64, 0, stream>>>((const unsigned short*)A_imag);
    proj_kernel<<<NBDL / 256, 256, 0, stream>>>(x, Wproj, bproj, pos);
    prep_kernel<<<(NLAYERS * PN) / 256, 256, 0, stream>>>(
        log_dt, log_A_real, A_imag, C_re, C_im);
    pack_w_kernel<<<(NLAYERS * WN) / 256, 256, 0, stream>>>(Wout);

    for (int i = 0; i < NLAYERS; i++) {
        prescan_kernel<<<BATCH * D_MODEL, 256, 0, stream>>>(i);
        scan_kernel<<<(BATCH * D_MODEL * 2) / 8, 256, 0, stream>>>(Dskip, i);
        dim3 gt(LSEQ / 64, D_MODEL / 64, BATCH);     // (64, 8, 8)
        transpose_y_kernel<<<gt, 256, 0, stream>>>();
        glu_mfma_kernel<<<1024, 256, 0, stream>>>(bout, i);
        ln_kernel<<<(BATCH * LSEQ) / 32, 256, 0, stream>>>(ln_g, ln_b, i);  // 1024 blocks
    }

    mean_kernel<<<BATCH * D_MODEL, 256, 0, stream>>>();
    stats_kernel<<<(BATCH * D_MODEL) / 256, 256, 0, stream>>>(
        Wstats, bstats, (float*)d_out);
}

// Round 5
// 1416.933 us; speedup vs baseline: 1.2603x; 1.2603x over previous
//
#include <hip/hip_runtime.h>
#include <hip/hip_bf16.h>
#include <hip/hip_fp16.h>
#include <cmath>

// Problem constants
#define BATCH   8
#define D_MODEL 512
#define N2      32
#define LSEQ    4096
#define NLAYERS 4
#define CIN     3
#define NBDL    (16777216u)   // BATCH*D_MODEL*LSEQ
#define PN      (D_MODEL * N2)            // params per layer
#define WN      (2 * D_MODEL * D_MODEL)   // weights per layer

typedef __attribute__((ext_vector_type(8))) short short8;   // 8 bf16 (4 VGPRs)
typedef __attribute__((ext_vector_type(4))) float floatx4;  // MFMA accum

// ---------------------------------------------------------------------------
// Static device scratch. Every buffer fully overwritten before read, each call.
// ---------------------------------------------------------------------------
__device__ float   g_h[NBDL];                                  // 64 MB h (B,D,L) fp32
__device__ __align__(16) __hip_bfloat16 g_yb[NBDL];            // 32 MB gelu out (B,D,L) bf16
__device__ __align__(16) __hip_bfloat16 g_yt[NBDL];            // 32 MB y^T (B,L,D) bf16
__device__ __align__(16) __hip_bfloat16 g_wb[NLAYERS * WN];    // 8 MB W bf16, all layers
__device__ __align__(16) __hip_bfloat16 g_G[(size_t)NLAYERS * 512 * 6 * 4096]; // 96 MB SSD mats
__device__ float4  g_p[NLAYERS * PN];                          // SSM params, all layers
__device__ float   g_hm[BATCH * D_MODEL];                      // mean over L
__device__ int     g_flag;                                     // 1=fp32, 0=bf16, 2=fp16

__device__ __forceinline__ float bfbits2f(unsigned short u) {
    union { unsigned int i; float f; } x; x.i = ((unsigned int)u) << 16; return x.f;
}
__device__ __forceinline__ float halfbits2f(unsigned short u) {
    __half h; *(unsigned short*)&h = u; return __half2float(h);
}
__device__ __forceinline__ float ldin(const void* p, size_t i, int m) {
    if (m == 1) return ((const float*)p)[i];
    unsigned short u = ((const unsigned short*)p)[i];
    if (m == 0) return bfbits2f(u);
    return halfbits2f(u);
}
__device__ __forceinline__ unsigned int pk2(float a, float b) {
    __hip_bfloat16 ha = __float2bfloat16(a), hb = __float2bfloat16(b);
    unsigned short ua, ub;
    __builtin_memcpy(&ua, &ha, 2); __builtin_memcpy(&ub, &hb, 2);
    return (unsigned int)ua | ((unsigned int)ub << 16);
}
// split a pair of fp32 into packed bf16 hi-words and bf16 lo-residual words
__device__ __forceinline__ void split2(float a, float b, unsigned int& hp, unsigned int& lp) {
    __hip_bfloat16 ah = __float2bfloat16(a), bh = __float2bfloat16(b);
    unsigned short ua, ub;
    __builtin_memcpy(&ua, &ah, 2); __builtin_memcpy(&ub, &bh, 2);
    hp = (unsigned int)ua | ((unsigned int)ub << 16);
    lp = pk2(a - __bfloat162float(ah), b - __bfloat162float(bh));
}
// complex integer power by binary exponentiation (exact-ish fp32, e in [0,64])
__device__ __forceinline__ float2 cpow_(float br, float bi, int e) {
    float rr = 1.f, ri = 0.f;
    while (e) {
        if (e & 1) { float t = rr * br - ri * bi; ri = rr * bi + ri * br; rr = t; }
        float t = br * br - bi * bi; bi = 2.f * br * bi; br = t;
        e >>= 1;
    }
    return make_float2(rr, ri);
}

// Branchless erf-based exact GELU (A&S 7.1.26, |err| < 1.5e-7)
__device__ __forceinline__ float fast_gelu(float x) {
    float z = x * 0.70710678118654752f;
    float a = fabsf(z);
    float t = __builtin_amdgcn_rcpf(fmaf(0.3275911f, a, 1.0f));
    float p = t * fmaf(t, fmaf(t, fmaf(t, fmaf(t, 1.061405429f, -1.453152027f),
                                       1.421413741f), -0.284496736f), 0.254829592f);
    float e = __expf(-a * a);
    float er = fmaf(-p, e, 1.0f);            // erf(|z|)
    er = copysignf(er, z);
    float hx = 0.5f * x;
    return fmaf(hx, er, hx);
}

// ---------------------------------------------------------------------------
// 0) dtype probe on A_imag (= pi*arange(32) broadcast; elt[1]=pi, elt[3]=3pi)
// ---------------------------------------------------------------------------
__global__ void detect_kernel(const unsigned short* a) {
    if (threadIdx.x == 0) {
        unsigned short h1 = a[1], h3 = a[3];
        int f;
        if (h1 == 0x0000 && h3 == 0x4049) f = 1;   // fp32 layout
        else if (h1 == 0x4049)            f = 0;   // native bf16
        else if (h1 == 0x4248)            f = 2;   // native fp16
        else                              f = 1;
        g_flag = f;
    }
}

__global__ __launch_bounds__(256) void sentinel_kernel(float* out, float v) {
    out[blockIdx.x * 256 + threadIdx.x] = v;
}

// ---------------------------------------------------------------------------
// 1) Input projection
// ---------------------------------------------------------------------------
__global__ __launch_bounds__(256) void proj_kernel(const void* x, const void* Wproj,
                                                   const void* bproj, const void* pos) {
    const int m = g_flag;
    unsigned idx = blockIdx.x * 256 + threadIdx.x;
    int l = idx & (LSEQ - 1);
    int o = (idx >> 12) & (D_MODEL - 1);
    int b = idx >> 21;
    float acc = ldin(bproj, o, m) + ldin(pos, (size_t)l * D_MODEL + o, m);
#pragma unroll
    for (int c = 0; c < CIN; c++)
        acc = fmaf(ldin(Wproj, o * CIN + c, m),
                   ldin(x, (size_t)(b * CIN + c) * LSEQ + l, m), acc);
    g_h[idx] = acc;
}

// ---------------------------------------------------------------------------
// 2) SSM param prep — ALL layers in one launch.
// ---------------------------------------------------------------------------
__global__ __launch_bounds__(256) void prep_kernel(const void* log_dt, const void* log_A_real,
                                                   const void* A_imag, const void* C_re,
                                                   const void* C_im) {
    const int m = g_flag;
    int idx = blockIdx.x * 256 + threadIdx.x;        // over NLAYERS*PN
    int layer = idx >> 14;                           // PN = 16384
    int i = idx & (PN - 1);
    int hh = i >> 5;
    size_t oH = (size_t)layer * D_MODEL;
    size_t oN = (size_t)layer * PN;
    float dt  = expf(ldin(log_dt, oH + hh, m));
    float a   = expf(ldin(log_A_real, oN + i, m));
    float bi  = ldin(A_imag, oN + i, m);
    float dre = -a * dt, dim = bi * dt;
    float er  = expf(dre);
    float wr  = er * cosf(dim);
    float wi  = er * sinf(dim);
    float Er  = wr - 1.0f, Ei = wi;
    float inv = 1.0f / (a * a + bi * bi);
    float Tr = (-Er * a + Ei * bi) * inv;
    float Ti = -(Er * bi + Ei * a) * inv;
    float cr = ldin(C_re, oN + i, m), ci = ldin(C_im, oN + i, m);
    float c2r = 2.0f * (cr * Tr - ci * Ti);
    float c2i = 2.0f * (cr * Ti + ci * Tr);
    g_p[idx] = make_float4(wr, wi, c2r, c2i);
}

// ---------------------------------------------------------------------------
// 2b) Pack Wout to bf16 — ALL layers in one launch.
// ---------------------------------------------------------------------------
__global__ __launch_bounds__(256) void pack_w_kernel(const void* Wout) {
    int idx = blockIdx.x * 256 + threadIdx.x;        // over NLAYERS*WN
    g_wb[idx] = __float2bfloat16(ldin(Wout, idx, g_flag));
}

// ---------------------------------------------------------------------------
// 2c) SSD matrix precompute: per (layer,h), six 64x64 bf16 matrices
//     mat0/1 = Mhi/Mlo: M[t][j] = K[t-j] (t>=j), K[d] = sum_n Re(c2_n w_n^d)
//     mat2/3 = Ahi/Alo: A[2n|2n+1][j] = Re|Im(w_n^{63-j})
//     mat4/5 = Chi/Clo: C[t][2n|2n+1] = Re(c2_n w_n^{t+1}) | -Im(c2_n w_n^{t+1})
// ---------------------------------------------------------------------------
__global__ __launch_bounds__(256) void gmat_kernel() {
    __shared__ float4 psh[32];
    __shared__ float Ksh[64];
    int tid = threadIdx.x;
    int bid = blockIdx.x;                   // layer*512 + h
    int layer = bid >> 9, h = bid & 511;
    if (tid < 32) psh[tid] = g_p[(size_t)layer * PN + h * N2 + tid];
    __syncthreads();
    if (tid < 64) {
        float acc = 0.f;
        for (int n = 0; n < 32; n++) {
            float4 pv = psh[n];
            float2 wd = cpow_(pv.x, pv.y, tid);
            acc = fmaf(pv.z, wd.x, fmaf(-pv.w, wd.y, acc));
        }
        Ksh[tid] = acc;
    }
    __syncthreads();
    __hip_bfloat16* G = g_G + (size_t)bid * 6 * 4096;
    for (int e = tid; e < 4096; e += 256) {
        int t = e >> 6, j = e & 63;
        // M
        float kv = (t >= j) ? Ksh[t - j] : 0.f;
        __hip_bfloat16 khi = __float2bfloat16(kv);
        G[e] = khi;
        G[4096 + e] = __float2bfloat16(kv - __bfloat162float(khi));
        // A
        {
            int n = t >> 1;
            float4 pv = psh[n];
            float2 wd = cpow_(pv.x, pv.y, 63 - j);
            float av = (t & 1) ? wd.y : wd.x;
            __hip_bfloat16 ahi = __float2bfloat16(av);
            G[2 * 4096 + e] = ahi;
            G[3 * 4096 + e] = __float2bfloat16(av - __bfloat162float(ahi));
        }
        // C
        {
            int n = j >> 1;
            float4 pv = psh[n];
            float2 wd = cpow_(pv.x, pv.y, t + 1);
            float zr = pv.z * wd.x - pv.w * wd.y;
            float zi = pv.z * wd.y + pv.w * wd.x;
            float cv = (j & 1) ? -zi : zr;
            __hip_bfloat16 chi = __float2bfloat16(cv);
            G[4 * 4096 + e] = chi;
            G[5 * 4096 + e] = __float2bfloat16(cv - __bfloat162float(chi));
        }
    }
}

// ---------------------------------------------------------------------------
// 3) SSD kernel: per (h,b) block, chunked linear-recurrence as MFMA GEMMs.
//    T=64 chunks, 64 chunks. LDS-resident; u read once, y written once.
//    Phases: [load M/A/u] GEMM2a(Ahi@U) [Alo] GEMM2b -> P(fp32,LDS) ->
//    lane-local 64-step inter-chunk scan (S hi/lo bf16, in place over P) ||
//    [Chi] -> GEMM1(M@U)+GEMM3a(Chi@S) -> [Clo] GEMM3b -> +dsk*u, gelu, store.
//    All operands hi/lo-split bf16 (lo*lo dropped) => ~fp32-class accuracy.
// ---------------------------------------------------------------------------
__global__ __launch_bounds__(256) void ssd_kernel(const void* Dskip, int layer) {
    __shared__ unsigned short sMhi[64][72];   // 9216 B each, 144 B row stride
    __shared__ unsigned short sMlo[64][72];
    __shared__ unsigned short sAC[64][72];    // A (hi then lo), later C (hi then lo)
    __shared__ unsigned short sUhi[64][72];
    __shared__ unsigned short sUlo[64][72];
    __shared__ float sPf[64][68];             // P fp32; later S hi/lo bf16 (17408 B)
    const int m = g_flag;
    int tid = threadIdx.x;
    int bid = blockIdx.x;                     // h*8 + b (same-h blocks adjacent)
    int h = bid >> 3, b = bid & 7;
    const unsigned short* Gsrc = (const unsigned short*)g_G + (size_t)(layer * 512 + h) * 6 * 4096;

    // L1: Mhi, Mlo, Ahi
    {
        int row = tid >> 2, seg = (tid & 3) * 16;
        const unsigned short* s = Gsrc + row * 64 + seg;
        *(uint4*)&sMhi[row][seg]     = *(const uint4*)(s);
        *(uint4*)&sMhi[row][seg + 8] = *(const uint4*)(s + 8);
        *(uint4*)&sMlo[row][seg]     = *(const uint4*)(s + 4096);
        *(uint4*)&sMlo[row][seg + 8] = *(const uint4*)(s + 4096 + 8);
        *(uint4*)&sAC[row][seg]      = *(const uint4*)(s + 2 * 4096);
        *(uint4*)&sAC[row][seg + 8]  = *(const uint4*)(s + 2 * 4096 + 8);
    }
    // u stage + hi/lo split: U[c][j] = u[c*64+j]
    {
        const float* ub = g_h + (size_t)(b * D_MODEL + h) * LSEQ;
        int c = tid >> 2, j0 = (tid & 3) * 16;
        const float* up = ub + c * 64 + j0;
#pragma unroll
        for (int s8 = 0; s8 < 2; s8++) {
            float4 va = *(const float4*)(up + s8 * 8);
            float4 vb = *(const float4*)(up + s8 * 8 + 4);
            uint4 H, L;
            split2(va.x, va.y, H.x, L.x);
            split2(va.z, va.w, H.y, L.y);
            split2(vb.x, vb.y, H.z, L.z);
            split2(vb.z, vb.w, H.w, L.w);
            *(uint4*)&sUhi[c][j0 + s8 * 8] = H;
            *(uint4*)&sUlo[c][j0 + s8 * 8] = L;
        }
    }
    __syncthreads();                                            // B1

    int lane = tid & 63, wave = tid >> 6;
    int q = lane >> 4, nm = lane & 15;
    int cidx = wave * 16 + nm;                                  // this lane's col (chunk)
    floatx4 zed = {0.f, 0.f, 0.f, 0.f};
    floatx4 pacc[4] = {zed, zed, zed, zed};

    // GEMM2a: P += Ahi@(Uhi + Ulo)
#pragma unroll
    for (int k0 = 0; k0 < 64; k0 += 32) {
        short8 bh = *(short8*)&sUhi[cidx][k0 + q * 8];
        short8 bl = *(short8*)&sUlo[cidx][k0 + q * 8];
#pragma unroll
        for (int mi = 0; mi < 4; mi++) {
            short8 a = *(short8*)&sAC[mi * 16 + nm][k0 + q * 8];
            pacc[mi] = __builtin_amdgcn_mfma_f32_16x16x32_bf16(a, bh, pacc[mi], 0, 0, 0);
            pacc[mi] = __builtin_amdgcn_mfma_f32_16x16x32_bf16(a, bl, pacc[mi], 0, 0, 0);
        }
    }
    __syncthreads();                                            // B2 (Ahi reads done)
    if (tid >= 128) {   // L2: Alo
        int idx = tid - 128, row = idx >> 1, seg = (idx & 1) * 32;
        const unsigned short* s = Gsrc + 3 * 4096 + row * 64 + seg;
        *(uint4*)&sAC[row][seg]      = *(const uint4*)(s);
        *(uint4*)&sAC[row][seg + 8]  = *(const uint4*)(s + 8);
        *(uint4*)&sAC[row][seg + 16] = *(const uint4*)(s + 16);
        *(uint4*)&sAC[row][seg + 24] = *(const uint4*)(s + 24);
    }
    __syncthreads();                                            // B3
    // GEMM2b: P += Alo@Uhi; store P (transposed: [col][row]) to LDS fp32
#pragma unroll
    for (int k0 = 0; k0 < 64; k0 += 32) {
        short8 bh = *(short8*)&sUhi[cidx][k0 + q * 8];
#pragma unroll
        for (int mi = 0; mi < 4; mi++) {
            short8 a = *(short8*)&sAC[mi * 16 + nm][k0 + q * 8];
            pacc[mi] = __builtin_amdgcn_mfma_f32_16x16x32_bf16(a, bh, pacc[mi], 0, 0, 0);
        }
    }
#pragma unroll
    for (int mi = 0; mi < 4; mi++)
        *(floatx4*)&sPf[cidx][mi * 16 + q * 4] = pacc[mi];
    __syncthreads();                                            // B4 (P visible)

    // inter-chunk scan (wave0 lanes 0..31, one chain per lane), in-place S over P
    if (tid < 32) {
        int n = tid;
        float4 pv = g_p[(size_t)layer * PN + h * N2 + n];
        float Wr = pv.x, Wi = pv.y;
#pragma unroll
        for (int s6 = 0; s6 < 6; s6++) { float t2 = Wr * Wr - Wi * Wi; Wi = 2.f * Wr * Wi; Wr = t2; }  // w^64
        float Sr = 0.f, Si = 0.f;
        for (int c = 0; c < 64; c++) {
            unsigned int* wp = (unsigned int*)&sPf[c][0];
            unsigned int pru = wp[2 * n], piu = wp[2 * n + 1];   // read P BEFORE S write
            float pr = __uint_as_float(pru), pi = __uint_as_float(piu);
            unsigned int shw, slw;
            split2(Sr, Si, shw, slw);
            wp[n]      = shw;                                    // Shi ushorts [0..63]
            wp[32 + n] = slw;                                    // Slo ushorts [64..127]
            float t2 = fmaf(Wr, Sr, fmaf(-Wi, Si, pr));
            Si = fmaf(Wr, Si, fmaf(Wi, Sr, pi));
            Sr = t2;
        }
    }
    if (tid >= 128) {   // L3: Chi (concurrent with scan; A dead after B4)
        int idx = tid - 128, row = idx >> 1, seg = (idx & 1) * 32;
        const unsigned short* s = Gsrc + 4 * 4096 + row * 64 + seg;
        *(uint4*)&sAC[row][seg]      = *(const uint4*)(s);
        *(uint4*)&sAC[row][seg + 8]  = *(const uint4*)(s + 8);
        *(uint4*)&sAC[row][seg + 16] = *(const uint4*)(s + 16);
        *(uint4*)&sAC[row][seg + 24] = *(const uint4*)(s + 24);
    }
    __syncthreads();                                            // B5 (S + Chi ready)

    // GEMM1: Yintra = (Mhi+Mlo)@(Uhi+Ulo) [3 products]; GEMM3a: Ycarry = Chi@(Shi+Slo)
    floatx4 accA[4] = {zed, zed, zed, zed};
    floatx4 accB[4] = {zed, zed, zed, zed};
#pragma unroll
    for (int k0 = 0; k0 < 64; k0 += 32) {
        short8 bh = *(short8*)&sUhi[cidx][k0 + q * 8];
        short8 bl = *(short8*)&sUlo[cidx][k0 + q * 8];
        const unsigned short* srow = (const unsigned short*)&sPf[cidx][0];
        short8 sh = *(short8*)(srow + k0 + q * 8);
        short8 sl = *(short8*)(srow + 64 + k0 + q * 8);
#pragma unroll
        for (int mi = 0; mi < 4; mi++) {
            short8 amh = *(short8*)&sMhi[mi * 16 + nm][k0 + q * 8];
            short8 aml = *(short8*)&sMlo[mi * 16 + nm][k0 + q * 8];
            short8 ac  = *(short8*)&sAC [mi * 16 + nm][k0 + q * 8];
            accA[mi] = __builtin_amdgcn_mfma_f32_16x16x32_bf16(amh, bh, accA[mi], 0, 0, 0);
            accA[mi] = __builtin_amdgcn_mfma_f32_16x16x32_bf16(amh, bl, accA[mi], 0, 0, 0);
            accA[mi] = __builtin_amdgcn_mfma_f32_16x16x32_bf16(aml, bh, accA[mi], 0, 0, 0);
            accB[mi] = __builtin_amdgcn_mfma_f32_16x16x32_bf16(ac,  sh, accB[mi], 0, 0, 0);
            accB[mi] = __builtin_amdgcn_mfma_f32_16x16x32_bf16(ac,  sl, accB[mi], 0, 0, 0);
        }
    }
    __syncthreads();                                            // B6 (Chi reads done)
    if (tid >= 128) {   // L4: Clo
        int idx = tid - 128, row = idx >> 1, seg = (idx & 1) * 32;
        const unsigned short* s = Gsrc + 5 * 4096 + row * 64 + seg;
        *(uint4*)&sAC[row][seg]      = *(const uint4*)(s);
        *(uint4*)&sAC[row][seg + 8]  = *(const uint4*)(s + 8);
        *(uint4*)&sAC[row][seg + 16] = *(const uint4*)(s + 16);
        *(uint4*)&sAC[row][seg + 24] = *(const uint4*)(s + 24);
    }
    __syncthreads();                                            // B7
    // GEMM3b: Ycarry += Clo@Shi
#pragma unroll
    for (int k0 = 0; k0 < 64; k0 += 32) {
        const unsigned short* srow = (const unsigned short*)&sPf[cidx][0];
        short8 sh = *(short8*)(srow + k0 + q * 8);
#pragma unroll
        for (int mi = 0; mi < 4; mi++) {
            short8 ac = *(short8*)&sAC[mi * 16 + nm][k0 + q * 8];
            accB[mi] = __builtin_amdgcn_mfma_f32_16x16x32_bf16(ac, sh, accB[mi], 0, 0, 0);
        }
    }

    // epilogue: y = Yintra + Ycarry + dsk*u -> gelu -> bf16 store
    float dsk = ldin(Dskip, (size_t)layer * D_MODEL + h, m);
    __hip_bfloat16* yb = g_yb + (size_t)(b * D_MODEL + h) * LSEQ;
#pragma unroll
    for (int mi = 0; mi < 4; mi++) {
        int t0 = mi * 16 + q * 4;
        uint2 uh = *(uint2*)&sUhi[cidx][t0];
        uint2 ul = *(uint2*)&sUlo[cidx][t0];
        float u0 = bfbits2f((unsigned short)(uh.x & 0xFFFF)) + bfbits2f((unsigned short)(ul.x & 0xFFFF));
        float u1 = bfbits2f((unsigned short)(uh.x >> 16))    + bfbits2f((unsigned short)(ul.x >> 16));
        float u2 = bfbits2f((unsigned short)(uh.y & 0xFFFF)) + bfbits2f((unsigned short)(ul.y & 0xFFFF));
        float u3 = bfbits2f((unsigned short)(uh.y >> 16))    + bfbits2f((unsigned short)(ul.y >> 16));
        float y0 = fast_gelu(accA[mi][0] + accB[mi][0] + dsk * u0);
        float y1 = fast_gelu(accA[mi][1] + accB[mi][1] + dsk * u1);
        float y2 = fast_gelu(accA[mi][2] + accB[mi][2] + dsk * u2);
        float y3 = fast_gelu(accA[mi][3] + accB[mi][3] + dsk * u3);
        uint2 o;
        o.x = pk2(y0, y1);
        o.y = pk2(y2, y3);
        *(uint2*)&yb[cidx * 64 + t0] = o;
    }
}

// ---------------------------------------------------------------------------
// 3b) Transpose: g_yb[b][k][l] bf16 -> g_yt[b][l][k] bf16. 64x64 tiles.
// ---------------------------------------------------------------------------
__global__ __launch_bounds__(256) void transpose_y_kernel() {
    __shared__ float Ts[64][67];
    int tid = threadIdx.x;
    int b  = blockIdx.z;
    int l0 = blockIdx.x * 64;
    int k0 = blockIdx.y * 64;
    const unsigned short* __restrict__ src =
        (const unsigned short*)g_yb + (size_t)b * D_MODEL * LSEQ;
    int kr = tid >> 3;              // 0..31
    int cc = (tid & 7) * 8;         // 0..56 (l-offset, 8 elems)
#pragma unroll
    for (int sw = 0; sw < 2; sw++) {
        int k = kr + sw * 32;
        uint4 v = *(const uint4*)&src[(size_t)(k0 + k) * LSEQ + l0 + cc];
        Ts[k][cc + 0] = bfbits2f((unsigned short)(v.x & 0xFFFF));
        Ts[k][cc + 1] = bfbits2f((unsigned short)(v.x >> 16));
        Ts[k][cc + 2] = bfbits2f((unsigned short)(v.y & 0xFFFF));
        Ts[k][cc + 3] = bfbits2f((unsigned short)(v.y >> 16));
        Ts[k][cc + 4] = bfbits2f((unsigned short)(v.z & 0xFFFF));
        Ts[k][cc + 5] = bfbits2f((unsigned short)(v.z >> 16));
        Ts[k][cc + 6] = bfbits2f((unsigned short)(v.w & 0xFFFF));
        Ts[k][cc + 7] = bfbits2f((unsigned short)(v.w >> 16));
    }
    __syncthreads();
    int lw = tid >> 2;              // 0..63 output l-row
    int kq = (tid & 3) * 16;        // 0,16,32,48
    uint4 A, B;
    A.x = pk2(Ts[kq + 0][lw],  Ts[kq + 1][lw]);
    A.y = pk2(Ts[kq + 2][lw],  Ts[kq + 3][lw]);
    A.z = pk2(Ts[kq + 4][lw],  Ts[kq + 5][lw]);
    A.w = pk2(Ts[kq + 6][lw],  Ts[kq + 7][lw]);
    B.x = pk2(Ts[kq + 8][lw],  Ts[kq + 9][lw]);
    B.y = pk2(Ts[kq + 10][lw], Ts[kq + 11][lw]);
    B.z = pk2(Ts[kq + 12][lw], Ts[kq + 13][lw]);
    B.w = pk2(Ts[kq + 14][lw], Ts[kq + 15][lw]);
    __hip_bfloat16* __restrict__ dst = g_yt + (size_t)b * ((size_t)LSEQ * D_MODEL);
    size_t o = (size_t)(l0 + lw) * D_MODEL + k0 + kq;
    *(uint4*)&dst[o]     = A;
    *(uint4*)&dst[o + 8] = B;
}

// ---------------------------------------------------------------------------
// 4) MFMA GLU: O = Wbf * Yt^T (both halves), z=(a+ba)*sigmoid(b+bb), H += z.
//    XCD-aware swizzle; LDS rows padded 32->40 shorts (80 B) to kill the
//    8-way ds_read_b128 bank conflicts of the 64 B stride.
// ---------------------------------------------------------------------------
__global__ __launch_bounds__(256) void glu_mfma_kernel(const void* bout, int layer) {
    __shared__ __hip_bfloat16 Wa[64][40];
    __shared__ __hip_bfloat16 Wb[64][40];
    __shared__ __hip_bfloat16 Yt[256][40];
    const int m = g_flag;
    int tid  = threadIdx.x;
    int wave = tid >> 6, lane = tid & 63;
    int q = lane >> 4, nm = lane & 15;
    int bid = blockIdx.x;                    // 0..1023
    int xcd = bid & 7;
    int qb  = bid >> 3;                      // 0..127
    int rt  = qb & 7;                        // 0..7   (64 o-rows)  fast within XCD
    int ct  = (xcd << 4) | (qb >> 3);        // 0..127 (256 l-cols) 16 per XCD
    int col0 = ct * 256;
    int row0 = rt * 64;
    int b  = col0 >> 12;                     // single batch per block
    int l0 = col0 & (LSEQ - 1);
    const __hip_bfloat16* __restrict__ Ybase = g_yt + (size_t)b * ((size_t)LSEQ * D_MODEL);
    const __hip_bfloat16* __restrict__ Wbase = g_wb + (size_t)layer * WN;

    floatx4 accA[4][4], accB[4][4];
    floatx4 zed = {0.f, 0.f, 0.f, 0.f};
#pragma unroll
    for (int i = 0; i < 4; i++)
#pragma unroll
        for (int j = 0; j < 4; j++) { accA[i][j] = zed; accB[i][j] = zed; }

    int sr = tid >> 2;              // 0..63
    int sk = (tid & 3) * 8;         // 0,8,16,24
    int wavecol = wave * 64;

    for (int k0 = 0; k0 < D_MODEL; k0 += 32) {
        *(uint4*)&Wa[sr][sk] = *(const uint4*)&Wbase[(size_t)(row0 + sr) * D_MODEL + k0 + sk];
        *(uint4*)&Wb[sr][sk] = *(const uint4*)&Wbase[(size_t)(row0 + sr + D_MODEL) * D_MODEL + k0 + sk];
#pragma unroll
        for (int it = 0; it < 4; it++) {
            int lr = it * 64 + sr;
            *(uint4*)&Yt[lr][sk] = *(const uint4*)&Ybase[(size_t)(l0 + lr) * D_MODEL + k0 + sk];
        }
        __syncthreads();
        short8 afa[4], afb[4];
#pragma unroll
        for (int mi = 0; mi < 4; mi++) {
            afa[mi] = *(short8*)&Wa[mi * 16 + nm][q * 8];
            afb[mi] = *(short8*)&Wb[mi * 16 + nm][q * 8];
        }
#pragma unroll
        for (int ni = 0; ni < 4; ni++) {
            short8 bf = *(short8*)&Yt[wavecol + ni * 16 + nm][q * 8];
#pragma unroll
            for (int mi = 0; mi < 4; mi++) {
                accA[mi][ni] = __builtin_amdgcn_mfma_f32_16x16x32_bf16(afa[mi], bf, accA[mi][ni], 0, 0, 0);
                accB[mi][ni] = __builtin_amdgcn_mfma_f32_16x16x32_bf16(afb[mi], bf, accB[mi][ni], 0, 0, 0);
            }
        }
        __syncthreads();
    }

    size_t boff = (size_t)layer * 2 * D_MODEL;
    float* __restrict__ Hb = g_h + (size_t)b * D_MODEL * LSEQ;
#pragma unroll
    for (int mi = 0; mi < 4; mi++) {
#pragma unroll
        for (int r = 0; r < 4; r++) {
            int o = row0 + mi * 16 + q * 4 + r;
            float ba  = ldin(bout, boff + o, m);
            float bb2 = ldin(bout, boff + o + D_MODEL, m);
#pragma unroll
            for (int ni = 0; ni < 4; ni++) {
                int l = l0 + wavecol + ni * 16 + nm;
                float aa = accA[mi][ni][r] + ba;
                float bv = accB[mi][ni][r] + bb2;
                float z  = aa * __builtin_amdgcn_rcpf(1.0f + __expf(-bv));
                Hb[(size_t)o * LSEQ + l] += z;
            }
        }
    }
}

// ---------------------------------------------------------------------------
// 5) LayerNorm over D, in place on g_h — 32-l tiles, 1024 blocks.
// ---------------------------------------------------------------------------
__global__ __launch_bounds__(256) void ln_kernel(const void* g, const void* bt, int layer) {
    __shared__ float s_sum[8][32];
    __shared__ float s_sq[8][32];
    __shared__ float s_mu[32], s_rs[32];
    const int m = g_flag;
    int tid = threadIdx.x;
    int l  = tid & 31;
    int dg = tid >> 5;                   // 0..7 -> d range [dg*64, dg*64+64)
    int bl = blockIdx.x;                 // 0..1023 = b*128 + ltile
    int b  = bl >> 7;
    int l0 = (bl & 127) * 32;
    float* __restrict__ hp = g_h + (size_t)b * D_MODEL * LSEQ + l0 + l;
    size_t goff = (size_t)layer * D_MODEL;
    float sum = 0.f, sq = 0.f;
#pragma unroll 4
    for (int d = dg * 64; d < dg * 64 + 64; d++) {
        float v = hp[(size_t)d * LSEQ];
        sum += v; sq += v * v;
    }
    s_sum[dg][l] = sum; s_sq[dg][l] = sq;
    __syncthreads();
    if (tid < 32) {
        float s = 0.f, qq = 0.f;
#pragma unroll
        for (int gq = 0; gq < 8; gq++) { s += s_sum[gq][tid]; qq += s_sq[gq][tid]; }
        float mu = s * (1.0f / D_MODEL);
        float var = qq * (1.0f / D_MODEL) - mu * mu;
        s_mu[tid] = mu;
        s_rs[tid] = rsqrtf(var + 1e-5f);
    }
    __syncthreads();
    float mu = s_mu[l], rs = s_rs[l];
#pragma unroll 4
    for (int d = dg * 64; d < dg * 64 + 64; d++) {
        float v = hp[(size_t)d * LSEQ];
        hp[(size_t)d * LSEQ] = (v - mu) * rs * ldin(g, goff + d, m) + ldin(bt, goff + d, m);
    }
}

// ---------------------------------------------------------------------------
// 6) Mean over L: one block per (b,d)
// ---------------------------------------------------------------------------
__global__ __launch_bounds__(256) void mean_kernel() {
    int bd = blockIdx.x;
    int tid = threadIdx.x;
    const float* __restrict__ row = g_h + (size_t)bd * LSEQ;
    float s = 0.f;
    for (int l = tid; l < LSEQ; l += 256) s += row[l];
#pragma unroll
    for (int off = 32; off > 0; off >>= 1) s += __shfl_down(s, off, 64);
    __shared__ float red[4];
    if ((tid & 63) == 0) red[tid >> 6] = s;
    __syncthreads();
    if (tid == 0) g_hm[bd] = (red[0] + red[1] + red[2] + red[3]) * (1.0f / LSEQ);
}

// ---------------------------------------------------------------------------
// 7) Final stats head -> FP32 output (mu flat || log_sig flat)
// ---------------------------------------------------------------------------
__global__ __launch_bounds__(256) void stats_kernel(const void* Wst, const void* bst,
                                                    float* __restrict__ out) {
    const int m = g_flag;
    int idx = blockIdx.x * 256 + threadIdx.x;
    int b = idx >> 9, o = idx & (D_MODEL - 1);
    const float* __restrict__ hb = g_hm + b * D_MODEL;
    float acc = ldin(bst, o, m);
    for (int d = 0; d < D_MODEL; d++)
        acc = fmaf(hb[d], ldin(Wst, (size_t)o * D_MODEL + d, m), acc);
    int pos = (o < 256) ? (b * 256 + o) : (2048 + b * 256 + (o - 256));
    out[pos] = acc;
}

// ---------------------------------------------------------------------------
extern "C" void kernel_launch(void* const* d_in, const int* in_sizes, int n_in,
                              void* d_out, int out_size, void* d_ws, size_t ws_size,
                              hipStream_t stream) {
    static const int exp_sizes[16] = {98304, 1536, 512, 2097152, 2048, 65536, 65536,
                                      65536, 65536, 2048, 2097152, 4096, 2048, 2048,
                                      262144, 512};
    bool ok = (n_in == 16);
    if (ok) for (int i = 0; i < 16; i++) if (in_sizes[i] != exp_sizes[i]) { ok = false; break; }
    if (!ok) {
        sentinel_kernel<<<(out_size + 255) / 256, 256, 0, stream>>>((float*)d_out, 1000.0f);
        return;
    }
    if (out_size != 4096) {
        sentinel_kernel<<<(out_size + 255) / 256, 256, 0, stream>>>((float*)d_out, 300.0f);
        return;
    }

    const void* x          = d_in[0];
    const void* Wproj      = d_in[1];
    const void* bproj      = d_in[2];
    const void* pos        = d_in[3];
    const void* log_dt     = d_in[4];
    const void* log_A_real = d_in[5];
    const void* A_imag     = d_in[6];
    const void* C_re       = d_in[7];
    const void* C_im       = d_in[8];
    const void* Dskip      = d_in[9];
    const void* Wout       = d_in[10];
    const void* bout       = d_in[11];
    const void* ln_g       = d_in[12];
    const void* ln_b       = d_in[13];
    const void* Wstats     = d_in[14];
    const void* bstats     = d_in[15];

    detect_kernel<<<1, 64, 0, stream>>>((const unsigned short*)A_imag);
    proj_kernel<<<NBDL / 256, 256, 0, stream>>>(x, Wproj, bproj, pos);
    prep_kernel<<<(NLAYERS * PN) / 256, 256, 0, stream>>>(
        log_dt, log_A_real, A_imag, C_re, C_im);
    pack_w_kernel<<<(NLAYERS * WN) / 256, 256, 0, stream>>>(Wout);
    gmat_kernel<<<NLAYERS * 512, 256, 0, stream>>>();

    for (int i = 0; i < NLAYERS; i++) {
        ssd_kernel<<<BATCH * D_MODEL, 256, 0, stream>>>(Dskip, i);   // 4096 blocks (h*8+b)
        dim3 gt(LSEQ / 64, D_MODEL / 64, BATCH);     // (64, 8, 8)
        transpose_y_kernel<<<gt, 256, 0, stream>>>();
        glu_mfma_kernel<<<1024, 256, 0, stream>>>(bout, i);
        ln_kernel<<<(BATCH * LSEQ) / 32, 256, 0, stream>>>(ln_g, ln_b, i);
    }

    mean_kernel<<<BATCH * D_MODEL, 256, 0, stream>>>();
    stats_kernel<<<(BATCH * D_MODEL) / 256, 256, 0, stream>>>(
        Wstats, bstats, (float*)d_out);
}